// Round 7
// baseline (395.221 us; speedup 1.0000x reference)
//
#include <hip/hip_runtime.h>

// ---------------------------------------------------------------------------
// MSCrossAttnBlock on MI355X (gfx950).
// B=4, E=32, LQ=1024, D=1024, NH=16, DH=64, NP=4. All levels are 32x32.
// R6: revert GEMM inner loop to 16x16x32 (R4 body; measured conflict-free,
//     gemm_dual 66us). Keep R5's orthogonal wins: epilogue-fused softmax
//     (remapped to 16x16 C/D: 16-lane / 4-lane shfl groups), pre-normalized
//     sampler, merged cvt+LN prep. 8 dispatches.
// ---------------------------------------------------------------------------

#define DEV __device__ __forceinline__

typedef float f32x4 __attribute__((ext_vector_type(4)));
typedef __bf16 bf16x8 __attribute__((ext_vector_type(8)));

DEV unsigned short f2bf(float f) {
  union { float f; unsigned u; } a; a.f = f;
  unsigned r = a.u + 0x7fffu + ((a.u >> 16) & 1u);
  return (unsigned short)(r >> 16);
}
DEV float bf2f(unsigned short h) {
  union { unsigned u; float f; } a; a.u = ((unsigned)h) << 16;
  return a.f;
}

// ---------------- merged prep: weight cvt + all LayerNorms -----------------
struct CvtArgs {
  const float* src[8];
  unsigned short* dst;
  int off4[9];  // prefix sums, float4 units
};
struct LnArgs {
  const float* s[4];
  const float* fg; const float* fb; const float* qg; const float* qb;
  unsigned short* f_out; unsigned short* q_out;
};

DEV void ln_row_wave(const float* __restrict__ xr, const float* __restrict__ g,
                     const float* __restrict__ b,
                     unsigned short* __restrict__ op_row) {
  const int lane = threadIdx.x & 63;
  float4 v[4];
  float s = 0.f, s2 = 0.f;
  #pragma unroll
  for (int j = 0; j < 4; ++j) {
    v[j] = ((const float4*)xr)[lane + 64 * j];
    s  += v[j].x + v[j].y + v[j].z + v[j].w;
    s2 += v[j].x*v[j].x + v[j].y*v[j].y + v[j].z*v[j].z + v[j].w*v[j].w;
  }
  #pragma unroll
  for (int o = 32; o; o >>= 1) { s += __shfl_xor(s, o); s2 += __shfl_xor(s2, o); }
  const float mean = s * (1.f / 1024.f);
  const float rstd = rsqrtf(s2 * (1.f / 1024.f) - mean * mean + 1e-6f);
  #pragma unroll
  for (int j = 0; j < 4; ++j) {
    float4 gg = ((const float4*)g)[lane + 64 * j];
    float4 bb = ((const float4*)b)[lane + 64 * j];
    ushort4 r;
    r.x = f2bf((v[j].x - mean) * rstd * gg.x + bb.x);
    r.y = f2bf((v[j].y - mean) * rstd * gg.y + bb.y);
    r.z = f2bf((v[j].z - mean) * rstd * gg.z + bb.z);
    r.w = f2bf((v[j].w - mean) * rstd * gg.w + bb.w);
    ((ushort4*)op_row)[lane + 64 * j] = r;
  }
}

// blocks [0,5056): cvt; [5056,10176): 4 feat-LN rows/block + q-LN rows.
__global__ __launch_bounds__(256) void prep_kernel(CvtArgs a, LnArgs L) {
  if (blockIdx.x < 5056) {
    int i = blockIdx.x * 256 + threadIdx.x;  // float4 index, exact grid
    int seg = 0;
    #pragma unroll
    for (int s = 1; s < 8; ++s) seg += (i >= a.off4[s]) ? 1 : 0;
    const float4 v = ((const float4*)a.src[seg])[i - a.off4[seg]];
    unsigned short* o = a.dst + (size_t)i * 4;
    o[0] = f2bf(v.x); o[1] = f2bf(v.y); o[2] = f2bf(v.z); o[3] = f2bf(v.w);
  } else {
    int row = (blockIdx.x - 5056) * 4 + (threadIdx.x >> 6);  // 0..20479
    if (row < 16384) {
      int l = row >> 12, inner = row & 4095;
      int orow = (inner >> 10) * 4096 + l * 1024 + (inner & 1023);
      ln_row_wave(L.s[l] + (size_t)inner * 1024, L.fg, L.fb,
                  L.f_out + (size_t)orow * 1024);
    } else {
      int inner = row - 16384;
      ln_row_wave(L.s[3] + (size_t)inner * 1024, L.qg, L.qb,
                  L.q_out + (size_t)inner * 1024);
    }
  }
}

__global__ __launch_bounds__(256) void ln_wave_kernel(
    const float* __restrict__ x, const float* __restrict__ g,
    const float* __restrict__ b, unsigned short* __restrict__ out) {
  int row = blockIdx.x * 4 + (threadIdx.x >> 6);
  ln_row_wave(x + (size_t)row * 1024, g, b, out + (size_t)row * 1024);
}

// ---------------- bf16 MFMA GEMM, 16x16x32 inner, swizzled LDS -------------
// C[M,N] = A[M,K] @ W[N,K]^T (+bias). BK=64 as two 32-k sub-tiles.
// LDS layout (measured conflict-free, R3/R4): 16-row granules of 512 shorts;
// physical slot cst at row r16 holds global k-chunk cst ^ ((r16>>1)&3);
// read slot for chunk lq is lq ^ ((lm>>1)&3).
// C/D frag: col = lane&15, row = (lane>>4)*4 + reg.
// EPI: 0=f32, 1=bf16, 2=CA split(off512 f32 | attw256 softmax-16),
//      3=SA split(val1024 bf16 | off128 f32 | attw64 softmax-4),
//      4=final combine -> d_out.
struct GemmP {
  const unsigned short* A; const unsigned short* W;
  void* C; void* C1; void* C2;
  const float* b0; const float* b1; const float* b2;
  const float* src3; const float* g1; const float* g2; const float* attnp;
  int M, N, K, tilesM;
};

template <int BM, int BN, int EPI>
DEV void gemm_body(const GemmP& P, int id, unsigned short* sA,
                   unsigned short* sB) {
  constexpr int WMT = BM / 2, WNT = BN / 2;
  constexpr int MF = WMT / 16, NF = WNT / 16;
  constexpr int PA = BM / 64, PB = BN / 64;    // granule passes per sub-tile
  const int tid = threadIdx.x;
  const int wave = tid >> 6, lane = tid & 63;
  const int wm = (wave & 1) * WMT, wn = (wave >> 1) * WNT;
  const int m0 = (id % P.tilesM) * BM;
  const int n0 = (id / P.tilesM) * BN;
  const int lq = lane >> 4, lm = lane & 15;
  const int r16 = lane >> 2;                    // staging: row within granule
  const int cst = lane & 3;                     // staging: slot within row
  const int csrc = cst ^ ((r16 >> 1) & 3);      // global k-chunk for slot
  const int aslot = lq ^ ((lm >> 1) & 3);       // read slot for chunk lq

  f32x4 acc[MF][NF] = {};
  bf16x8 ald[2][PA], bld[2][PB];

  #pragma unroll 1
  for (int k0 = 0; k0 < P.K; k0 += 64) {
    #pragma unroll
    for (int s = 0; s < 2; ++s) {
      #pragma unroll
      for (int p = 0; p < PA; ++p) {
        int grow = m0 + (wave + 4 * p) * 16 + r16;
        ald[s][p] = *(const bf16x8*)(P.A + (size_t)grow * P.K + k0 + s * 32 + csrc * 8);
      }
      #pragma unroll
      for (int p = 0; p < PB; ++p) {
        int grow = min(n0 + (wave + 4 * p) * 16 + r16, P.N - 1);
        bld[s][p] = *(const bf16x8*)(P.W + (size_t)grow * P.K + k0 + s * 32 + csrc * 8);
      }
    }
    __syncthreads();  // prev iteration's LDS reads complete
    #pragma unroll
    for (int s = 0; s < 2; ++s) {
      #pragma unroll
      for (int p = 0; p < PA; ++p)
        *(bf16x8*)(sA + s * BM * 32 + (wave + 4 * p) * 512 + (r16 * 4 + cst) * 8) = ald[s][p];
      #pragma unroll
      for (int p = 0; p < PB; ++p)
        *(bf16x8*)(sB + s * BN * 32 + (wave + 4 * p) * 512 + (r16 * 4 + cst) * 8) = bld[s][p];
    }
    __syncthreads();
    #pragma unroll
    for (int s = 0; s < 2; ++s) {
      bf16x8 af[MF], bfr[NF];
      #pragma unroll
      for (int mi = 0; mi < MF; ++mi)
        af[mi] = *(const bf16x8*)(sA + s * BM * 32 + ((wm >> 4) + mi) * 512 + lm * 32 + aslot * 8);
      #pragma unroll
      for (int ni = 0; ni < NF; ++ni)
        bfr[ni] = *(const bf16x8*)(sB + s * BN * 32 + ((wn >> 4) + ni) * 512 + lm * 32 + aslot * 8);
      #pragma unroll
      for (int mi = 0; mi < MF; ++mi)
        #pragma unroll
        for (int ni = 0; ni < NF; ++ni)
          acc[mi][ni] = __builtin_amdgcn_mfma_f32_16x16x32_bf16(
              af[mi], bfr[ni], acc[mi][ni], 0, 0, 0);
    }
  }

  #pragma unroll
  for (int mi = 0; mi < MF; ++mi) {
    #pragma unroll
    for (int ni = 0; ni < NF; ++ni) {
      const int colbase = n0 + wn + ni * 16;
      const int col = colbase + lm;
      #pragma unroll
      for (int r2 = 0; r2 < 4; ++r2) {
        const int row = m0 + wm + mi * 16 + lq * 4 + r2;
        float v = acc[mi][ni][r2];
        if constexpr (EPI == 0) {
          ((float*)P.C)[(size_t)row * 1024 + col] = v + P.b0[col];
        } else if constexpr (EPI == 1) {
          ((unsigned short*)P.C)[(size_t)row * 1024 + col] = f2bf(v + P.b0[col]);
        } else if constexpr (EPI == 2) {
          if (colbase < 512) {
            ((float*)P.C)[(size_t)row * 512 + col] = v + P.b0[col];
          } else {
            // softmax over the 16 logits of (row, head): lanes lq*16..lq*16+15
            float x = v + P.b1[col - 512];
            float m = x;
            #pragma unroll
            for (int o = 8; o; o >>= 1) m = fmaxf(m, __shfl_xor(m, o));
            float e = __expf(x - m);
            float ss = e;
            #pragma unroll
            for (int o = 8; o; o >>= 1) ss += __shfl_xor(ss, o);
            ((float*)P.C1)[(size_t)row * 256 + col - 512] = e / ss;
          }
        } else if constexpr (EPI == 3) {
          if (colbase < 1024) {
            ((unsigned short*)P.C)[(size_t)row * 1024 + col] = f2bf(v + P.b0[col]);
          } else if (colbase < 1152) {
            ((float*)P.C1)[(size_t)row * 128 + col - 1024] = v + P.b1[col - 1024];
          } else if (colbase < 1216) {
            // softmax over 4 logits of (row, head): aligned 4-lane subgroup
            float x = v + P.b2[col - 1152];
            float m = x;
            #pragma unroll
            for (int o = 2; o; o >>= 1) m = fmaxf(m, __shfl_xor(m, o));
            float e = __expf(x - m);
            float ss = e;
            #pragma unroll
            for (int o = 2; o; o >>= 1) ss += __shfl_xor(ss, o);
            ((float*)P.C2)[(size_t)row * 64 + col - 1152] = e / ss;
          }
        } else {  // EPI == 4: out = src3 + g1*(attn + g2*(v+b))
          size_t i = (size_t)row * 1024 + col;
          float vv = v + P.b0[col];
          ((float*)P.C)[i] = P.src3[i] + P.g1[col] * (P.attnp[i] + P.g2[col] * vv);
        }
      }
    }
  }
}

template <int BM, int BN, int EPI>
__global__ __launch_bounds__(256) void gemm_v3(GemmP P) {
  extern __shared__ __align__(16) unsigned short smem[];
  gemm_body<BM, BN, EPI>(P, blockIdx.x, smem, smem + BM * 64);
}

// merged CA dispatch: blocks [0,split) = val GEMM (EPI1), rest = off/attw (EPI2)
template <int BM, int BN>
__global__ __launch_bounds__(256) void gemm_dual(GemmP Pv, GemmP Po, int split) {
  extern __shared__ __align__(16) unsigned short smem[];
  if ((int)blockIdx.x < split)
    gemm_body<BM, BN, 1>(Pv, blockIdx.x, smem, smem + BM * 64);
  else
    gemm_body<BM, BN, 2>(Po, blockIdx.x - split, smem, smem + BM * 64);
}

// ---------------- MS-deform bilinear sampling (weights pre-normalized) -----
template <int NLEV>
__global__ __launch_bounds__(256) void ms_sample_fused(
    const unsigned short* __restrict__ value, const float* __restrict__ off,
    const float* __restrict__ attw, unsigned short* __restrict__ out) {
  const int nq = blockIdx.x;               // n*1024 + q
  const int wave = threadIdx.x >> 6, lane = threadIdx.x & 63;
  const int h = (wave << 2) + (lane >> 4);
  const int c = (lane & 15) << 2;          // channel base (0..60)
  const int q = nq & 1023, n = nq >> 10;
  const float* offp = off + ((size_t)nq * 16 + h) * (NLEV * 8);
  const float* awp  = attw + ((size_t)nq * 16 + h) * (NLEV * 4);

  float lg[NLEV * 4];
  #pragma unroll
  for (int i = 0; i < NLEV; ++i) {
    float4 v = ((const float4*)awp)[i];
    lg[4*i] = v.x; lg[4*i+1] = v.y; lg[4*i+2] = v.z; lg[4*i+3] = v.w;
  }

  const float fqx = (float)(q & 31), fqy = (float)(q >> 5);
  float a0 = 0.f, a1 = 0.f, a2 = 0.f, a3 = 0.f;

  #pragma unroll
  for (int l = 0; l < NLEV; ++l) {
    const unsigned short* vl =
        value + ((size_t)(n * NLEV + l) << 20) + h * 64 + c;
    #pragma unroll
    for (int p = 0; p < 4; ++p) {
      float2 o2 = ((const float2*)offp)[l * 4 + p];
      float aw = lg[l * 4 + p];
      float xx = fqx + o2.x, yy = fqy + o2.y;
      float xf = floorf(xx), yf = floorf(yy);
      float fx = xx - xf, fy = yy - yf;
      int ix = (int)xf, iy = (int)yf;
      int ix1 = ix + 1, iy1 = iy + 1;
      float vx0 = ((unsigned)ix  < 32u) ? 1.f : 0.f;
      float vx1 = ((unsigned)ix1 < 32u) ? 1.f : 0.f;
      float vy0 = ((unsigned)iy  < 32u) ? 1.f : 0.f;
      float vy1 = ((unsigned)iy1 < 32u) ? 1.f : 0.f;
      int cx0 = min(max(ix, 0), 31), cx1 = min(max(ix1, 0), 31);
      int cy0 = min(max(iy, 0), 31), cy1 = min(max(iy1, 0), 31);
      float w00 = (1.f - fx) * (1.f - fy) * vx0 * vy0 * aw;
      float w01 = fx * (1.f - fy) * vx1 * vy0 * aw;
      float w10 = (1.f - fx) * fy * vx0 * vy1 * aw;
      float w11 = fx * fy * vx1 * vy1 * aw;
      ushort4 u00 = *(const ushort4*)(vl + ((size_t)(cy0 * 32 + cx0) << 10));
      ushort4 u01 = *(const ushort4*)(vl + ((size_t)(cy0 * 32 + cx1) << 10));
      ushort4 u10 = *(const ushort4*)(vl + ((size_t)(cy1 * 32 + cx0) << 10));
      ushort4 u11 = *(const ushort4*)(vl + ((size_t)(cy1 * 32 + cx1) << 10));
      a0 += w00 * bf2f(u00.x) + w01 * bf2f(u01.x) + w10 * bf2f(u10.x) + w11 * bf2f(u11.x);
      a1 += w00 * bf2f(u00.y) + w01 * bf2f(u01.y) + w10 * bf2f(u10.y) + w11 * bf2f(u11.y);
      a2 += w00 * bf2f(u00.z) + w01 * bf2f(u01.z) + w10 * bf2f(u10.z) + w11 * bf2f(u11.z);
      a3 += w00 * bf2f(u00.w) + w01 * bf2f(u01.w) + w10 * bf2f(u10.w) + w11 * bf2f(u11.w);
    }
  }
  ushort4 r;
  r.x = f2bf(a0); r.y = f2bf(a1); r.z = f2bf(a2); r.w = f2bf(a3);
  *(ushort4*)(out + ((size_t)nq * 16 + h) * 64 + c) = r;
}

// ---------------------------------------------------------------------------
extern "C" void kernel_launch(void* const* d_in, const int* in_sizes, int n_in,
                              void* d_out, int out_size, void* d_ws,
                              size_t ws_size, hipStream_t stream) {
  (void)in_sizes; (void)n_in; (void)out_size; (void)ws_size;
  const float* src[4] = {(const float*)d_in[0], (const float*)d_in[1],
                         (const float*)d_in[2], (const float*)d_in[3]};
  const float* qn_g = (const float*)d_in[4];
  const float* qn_b = (const float*)d_in[5];
  const float* fn_g = (const float*)d_in[6];
  const float* fn_b = (const float*)d_in[7];
  const float* n1_g = (const float*)d_in[8];
  const float* n1_b = (const float*)d_in[9];
  const float* gamma1 = (const float*)d_in[10];
  const float* gamma2 = (const float*)d_in[11];
  const float* ca_vw = (const float*)d_in[12];
  const float* ca_vb = (const float*)d_in[13];
  const float* ca_ow = (const float*)d_in[14];
  const float* ca_ob = (const float*)d_in[15];
  const float* ca_aw = (const float*)d_in[16];
  const float* ca_ab = (const float*)d_in[17];
  const float* ca_pw = (const float*)d_in[18];
  const float* ca_pb = (const float*)d_in[19];
  const float* sa_vw = (const float*)d_in[20];
  const float* sa_vb = (const float*)d_in[21];
  const float* sa_ow = (const float*)d_in[22];
  const float* sa_ob = (const float*)d_in[23];
  const float* sa_aw = (const float*)d_in[24];
  const float* sa_ab = (const float*)d_in[25];
  const float* sa_pw = (const float*)d_in[26];
  const float* sa_pb = (const float*)d_in[27];

  // ---- workspace layout ----
  char* wsp = (char*)d_ws;
  size_t off = 0;
  auto alloc = [&](size_t bytes) {
    char* r = wsp + off;
    off = (off + bytes + 255) & ~(size_t)255;
    return r;
  };
  const size_t MB = 1024 * 1024;
  unsigned short* w_ca_vw = (unsigned short*)alloc(1024 * 1024 * 2);
  unsigned short* w_ca_ow = (unsigned short*)alloc(512 * 1024 * 2);
  unsigned short* w_ca_aw = (unsigned short*)alloc(256 * 1024 * 2);
  unsigned short* w_ca_pw = (unsigned short*)alloc(1024 * 1024 * 2);
  unsigned short* w_sa_vw = (unsigned short*)alloc(1024 * 1024 * 2);
  unsigned short* w_sa_ow = (unsigned short*)alloc(128 * 1024 * 2);
  unsigned short* w_sa_aw = (unsigned short*)alloc(64 * 1024 * 2);
  unsigned short* w_sa_pw = (unsigned short*)alloc(1024 * 1024 * 2);
  (void)w_ca_aw; (void)w_sa_ow; (void)w_sa_aw;
  char* R1 = alloc(32 * MB);  // f_ln bf16 | attn f32 + attn1 bf16 + samp_sa bf16
  char* R2 = alloc(32 * MB);  // val_ca bf16 | val_sa bf16
  char* R3 = alloc(8 * MB);   // q_ln bf16 | samp_ca bf16
  char* R4 = alloc(8 * MB);   // off_ca f32 | off_sa f32 + attw_sa f32
  char* R5 = alloc(4 * MB);   // attw_ca f32 (normalized in GEMM epilogue)

  unsigned short* f_ln    = (unsigned short*)R1;
  float*          attn    = (float*)R1;
  unsigned short* attn1   = (unsigned short*)(R1 + 16 * MB);
  unsigned short* samp_sa = (unsigned short*)(R1 + 24 * MB);
  unsigned short* val_ca  = (unsigned short*)R2;
  unsigned short* val_sa  = (unsigned short*)R2;
  unsigned short* q_ln    = (unsigned short*)R3;
  unsigned short* samp_ca = (unsigned short*)R3;
  float*          off_ca  = (float*)R4;
  float*          off_sa  = (float*)R4;
  float*          attw_sa = (float*)(R4 + 4 * MB);
  float*          attw_ca = (float*)R5;

  // ---- 1. merged weight conversion + LayerNorms ----
  CvtArgs ca;
  ca.src[0] = ca_vw; ca.src[1] = ca_ow; ca.src[2] = ca_aw; ca.src[3] = ca_pw;
  ca.src[4] = sa_vw; ca.src[5] = sa_ow; ca.src[6] = sa_aw; ca.src[7] = sa_pw;
  ca.dst = w_ca_vw;
  const int sizes4[8] = {262144, 131072, 65536, 262144, 262144, 32768, 16384, 262144};
  ca.off4[0] = 0;
  for (int i = 0; i < 8; ++i) ca.off4[i + 1] = ca.off4[i] + sizes4[i];
  LnArgs la;
  la.s[0] = src[0]; la.s[1] = src[1]; la.s[2] = src[2]; la.s[3] = src[3];
  la.fg = fn_g; la.fb = fn_b; la.qg = qn_g; la.qb = qn_b;
  la.f_out = f_ln; la.q_out = q_ln;
  prep_kernel<<<10176, 256, 0, stream>>>(ca, la);

  auto mkP = [](const unsigned short* A, const unsigned short* W, void* C,
                const float* b0, int M, int N, int K, int tilesM) {
    GemmP p{}; p.A = A; p.W = W; p.C = C; p.b0 = b0;
    p.M = M; p.N = N; p.K = K; p.tilesM = tilesM;
    return p;
  };

  // ---- 2. CA: merged value + off/attw GEMM (one dispatch) ----
  {
    GemmP pv = mkP(f_ln, w_ca_vw, val_ca, ca_vb, 16384, 1024, 1024, 128);
    GemmP po = mkP(q_ln, w_ca_ow, off_ca, ca_ob, 4096, 768, 1024, 32);
    po.C1 = attw_ca; po.b1 = ca_ab;
    gemm_dual<128, 128><<<1024 + 192, 256, 32768, stream>>>(pv, po, 1024);
  }

  // ---- 3. CA sampling + projection ----
  ms_sample_fused<4><<<4096, 256, 0, stream>>>(val_ca, off_ca, attw_ca, samp_ca);
  gemm_v3<64, 128, 0><<<64 * 8, 256, (64 + 128) * 64 * 2, stream>>>(
      mkP(samp_ca, w_ca_pw, attn, ca_pb, 4096, 1024, 1024, 64));

  // ---- 4. SA branch ----
  ln_wave_kernel<<<1024, 256, 0, stream>>>(attn, n1_g, n1_b, attn1);
  {
    GemmP p = mkP(attn1, w_sa_vw, val_sa, sa_vb, 4096, 1216, 1024, 64);
    p.C1 = off_sa; p.b1 = sa_ob; p.C2 = attw_sa; p.b2 = sa_ab;
    gemm_v3<64, 128, 3><<<64 * 10, 256, (64 + 128) * 64 * 2, stream>>>(p);
  }
  ms_sample_fused<1><<<4096, 256, 0, stream>>>(val_sa, off_sa, attw_sa, samp_sa);
  {
    GemmP p = mkP(samp_sa, w_sa_pw, d_out, sa_pb, 4096, 1024, 1024, 64);
    p.src3 = src[3]; p.g1 = gamma1; p.g2 = gamma2; p.attnp = attn;
    gemm_v3<64, 128, 4><<<64 * 8, 256, (64 + 128) * 64 * 2, stream>>>(p);
  }
}

// Round 8
// 370.920 us; speedup vs baseline: 1.0655x; 1.0655x over previous
//
#include <hip/hip_runtime.h>

// ---------------------------------------------------------------------------
// MSCrossAttnBlock on MI355X (gfx950).
// B=4, E=32, LQ=1024, D=1024, NH=16, DH=64, NP=4. All levels are 32x32.
// R7: restore R4's measured-best GEMM config (16x16x32 body, PLAIN epilogues,
//     softmax inside samplers). Single retained delta vs R4: merged cvt+LN
//     prep (separate dispatch from the GEMM). 8 dispatches.
//     Evidence: R5/R6's epilogue-softmax correlated with gemm_dual 66->85us
//     at identical hbm_bytes; reverting the epilogue is the controlled test.
// ---------------------------------------------------------------------------

#define DEV __device__ __forceinline__

typedef float f32x4 __attribute__((ext_vector_type(4)));
typedef __bf16 bf16x8 __attribute__((ext_vector_type(8)));

DEV unsigned short f2bf(float f) {
  union { float f; unsigned u; } a; a.f = f;
  unsigned r = a.u + 0x7fffu + ((a.u >> 16) & 1u);
  return (unsigned short)(r >> 16);
}
DEV float bf2f(unsigned short h) {
  union { unsigned u; float f; } a; a.u = ((unsigned)h) << 16;
  return a.f;
}

// ---------------- merged prep: weight cvt + all LayerNorms -----------------
struct CvtArgs {
  const float* src[8];
  unsigned short* dst;
  int off4[9];  // prefix sums, float4 units
};
struct LnArgs {
  const float* s[4];
  const float* fg; const float* fb; const float* qg; const float* qb;
  unsigned short* f_out; unsigned short* q_out;
};

DEV void ln_row_wave(const float* __restrict__ xr, const float* __restrict__ g,
                     const float* __restrict__ b,
                     unsigned short* __restrict__ op_row) {
  const int lane = threadIdx.x & 63;
  float4 v[4];
  float s = 0.f, s2 = 0.f;
  #pragma unroll
  for (int j = 0; j < 4; ++j) {
    v[j] = ((const float4*)xr)[lane + 64 * j];
    s  += v[j].x + v[j].y + v[j].z + v[j].w;
    s2 += v[j].x*v[j].x + v[j].y*v[j].y + v[j].z*v[j].z + v[j].w*v[j].w;
  }
  #pragma unroll
  for (int o = 32; o; o >>= 1) { s += __shfl_xor(s, o); s2 += __shfl_xor(s2, o); }
  const float mean = s * (1.f / 1024.f);
  const float rstd = rsqrtf(s2 * (1.f / 1024.f) - mean * mean + 1e-6f);
  #pragma unroll
  for (int j = 0; j < 4; ++j) {
    float4 gg = ((const float4*)g)[lane + 64 * j];
    float4 bb = ((const float4*)b)[lane + 64 * j];
    ushort4 r;
    r.x = f2bf((v[j].x - mean) * rstd * gg.x + bb.x);
    r.y = f2bf((v[j].y - mean) * rstd * gg.y + bb.y);
    r.z = f2bf((v[j].z - mean) * rstd * gg.z + bb.z);
    r.w = f2bf((v[j].w - mean) * rstd * gg.w + bb.w);
    ((ushort4*)op_row)[lane + 64 * j] = r;
  }
}

// blocks [0,5056): cvt; [5056,10176): 4 feat-LN rows/block + q-LN rows.
__global__ __launch_bounds__(256) void prep_kernel(CvtArgs a, LnArgs L) {
  if (blockIdx.x < 5056) {
    int i = blockIdx.x * 256 + threadIdx.x;  // float4 index, exact grid
    int seg = 0;
    #pragma unroll
    for (int s = 1; s < 8; ++s) seg += (i >= a.off4[s]) ? 1 : 0;
    const float4 v = ((const float4*)a.src[seg])[i - a.off4[seg]];
    unsigned short* o = a.dst + (size_t)i * 4;
    o[0] = f2bf(v.x); o[1] = f2bf(v.y); o[2] = f2bf(v.z); o[3] = f2bf(v.w);
  } else {
    int row = (blockIdx.x - 5056) * 4 + (threadIdx.x >> 6);  // 0..20479
    if (row < 16384) {
      int l = row >> 12, inner = row & 4095;
      int orow = (inner >> 10) * 4096 + l * 1024 + (inner & 1023);
      ln_row_wave(L.s[l] + (size_t)inner * 1024, L.fg, L.fb,
                  L.f_out + (size_t)orow * 1024);
    } else {
      int inner = row - 16384;
      ln_row_wave(L.s[3] + (size_t)inner * 1024, L.qg, L.qb,
                  L.q_out + (size_t)inner * 1024);
    }
  }
}

__global__ __launch_bounds__(256) void ln_wave_kernel(
    const float* __restrict__ x, const float* __restrict__ g,
    const float* __restrict__ b, unsigned short* __restrict__ out) {
  int row = blockIdx.x * 4 + (threadIdx.x >> 6);
  ln_row_wave(x + (size_t)row * 1024, g, b, out + (size_t)row * 1024);
}

// ---------------- bf16 MFMA GEMM, 16x16x32 inner, swizzled LDS -------------
// C[M,N] = A[M,K] @ W[N,K]^T (+bias). BK=64 as two 32-k sub-tiles.
// LDS layout (measured conflict-free, R3/R4): 16-row granules of 512 shorts;
// physical slot cst at row r16 holds global k-chunk cst ^ ((r16>>1)&3);
// read slot for chunk lq is lq ^ ((lm>>1)&3).
// C/D frag: col = lane&15, row = (lane>>4)*4 + reg.
// EPI: 0=f32, 1=bf16, 2=CA split(off512 f32 | attw256 f32 raw logits),
//      3=SA split(val1024 bf16 | off128 f32 | attw64 f32 raw logits),
//      4=final combine -> d_out.  (PLAIN epilogues — R4 configuration.)
struct GemmP {
  const unsigned short* A; const unsigned short* W;
  void* C; void* C1; void* C2;
  const float* b0; const float* b1; const float* b2;
  const float* src3; const float* g1; const float* g2; const float* attnp;
  int M, N, K, tilesM;
};

template <int BM, int BN, int EPI>
DEV void gemm_body(const GemmP& P, int id, unsigned short* sA,
                   unsigned short* sB) {
  constexpr int WMT = BM / 2, WNT = BN / 2;
  constexpr int MF = WMT / 16, NF = WNT / 16;
  constexpr int PA = BM / 64, PB = BN / 64;    // granule passes per sub-tile
  const int tid = threadIdx.x;
  const int wave = tid >> 6, lane = tid & 63;
  const int wm = (wave & 1) * WMT, wn = (wave >> 1) * WNT;
  const int m0 = (id % P.tilesM) * BM;
  const int n0 = (id / P.tilesM) * BN;
  const int lq = lane >> 4, lm = lane & 15;
  const int r16 = lane >> 2;                    // staging: row within granule
  const int cst = lane & 3;                     // staging: slot within row
  const int csrc = cst ^ ((r16 >> 1) & 3);      // global k-chunk for slot
  const int aslot = lq ^ ((lm >> 1) & 3);       // read slot for chunk lq

  f32x4 acc[MF][NF] = {};
  bf16x8 ald[2][PA], bld[2][PB];

  #pragma unroll 1
  for (int k0 = 0; k0 < P.K; k0 += 64) {
    #pragma unroll
    for (int s = 0; s < 2; ++s) {
      #pragma unroll
      for (int p = 0; p < PA; ++p) {
        int grow = m0 + (wave + 4 * p) * 16 + r16;
        ald[s][p] = *(const bf16x8*)(P.A + (size_t)grow * P.K + k0 + s * 32 + csrc * 8);
      }
      #pragma unroll
      for (int p = 0; p < PB; ++p) {
        int grow = min(n0 + (wave + 4 * p) * 16 + r16, P.N - 1);
        bld[s][p] = *(const bf16x8*)(P.W + (size_t)grow * P.K + k0 + s * 32 + csrc * 8);
      }
    }
    __syncthreads();  // prev iteration's LDS reads complete
    #pragma unroll
    for (int s = 0; s < 2; ++s) {
      #pragma unroll
      for (int p = 0; p < PA; ++p)
        *(bf16x8*)(sA + s * BM * 32 + (wave + 4 * p) * 512 + (r16 * 4 + cst) * 8) = ald[s][p];
      #pragma unroll
      for (int p = 0; p < PB; ++p)
        *(bf16x8*)(sB + s * BN * 32 + (wave + 4 * p) * 512 + (r16 * 4 + cst) * 8) = bld[s][p];
    }
    __syncthreads();
    #pragma unroll
    for (int s = 0; s < 2; ++s) {
      bf16x8 af[MF], bfr[NF];
      #pragma unroll
      for (int mi = 0; mi < MF; ++mi)
        af[mi] = *(const bf16x8*)(sA + s * BM * 32 + ((wm >> 4) + mi) * 512 + lm * 32 + aslot * 8);
      #pragma unroll
      for (int ni = 0; ni < NF; ++ni)
        bfr[ni] = *(const bf16x8*)(sB + s * BN * 32 + ((wn >> 4) + ni) * 512 + lm * 32 + aslot * 8);
      #pragma unroll
      for (int mi = 0; mi < MF; ++mi)
        #pragma unroll
        for (int ni = 0; ni < NF; ++ni)
          acc[mi][ni] = __builtin_amdgcn_mfma_f32_16x16x32_bf16(
              af[mi], bfr[ni], acc[mi][ni], 0, 0, 0);
    }
  }

  #pragma unroll
  for (int mi = 0; mi < MF; ++mi) {
    #pragma unroll
    for (int ni = 0; ni < NF; ++ni) {
      const int col = n0 + wn + ni * 16 + lm;
      #pragma unroll
      for (int r2 = 0; r2 < 4; ++r2) {
        const int row = m0 + wm + mi * 16 + lq * 4 + r2;
        float v = acc[mi][ni][r2];
        if constexpr (EPI == 0) {
          ((float*)P.C)[(size_t)row * 1024 + col] = v + P.b0[col];
        } else if constexpr (EPI == 1) {
          ((unsigned short*)P.C)[(size_t)row * 1024 + col] = f2bf(v + P.b0[col]);
        } else if constexpr (EPI == 2) {
          if (col < 512)
            ((float*)P.C)[(size_t)row * 512 + col] = v + P.b0[col];
          else
            ((float*)P.C1)[(size_t)row * 256 + col - 512] = v + P.b1[col - 512];
        } else if constexpr (EPI == 3) {
          if (col < 1024)
            ((unsigned short*)P.C)[(size_t)row * 1024 + col] = f2bf(v + P.b0[col]);
          else if (col < 1152)
            ((float*)P.C1)[(size_t)row * 128 + col - 1024] = v + P.b1[col - 1024];
          else if (col < 1216)
            ((float*)P.C2)[(size_t)row * 64 + col - 1152] = v + P.b2[col - 1152];
        } else {  // EPI == 4: out = src3 + g1*(attn + g2*(v+b))
          size_t i = (size_t)row * 1024 + col;
          float vv = v + P.b0[col];
          ((float*)P.C)[i] = P.src3[i] + P.g1[col] * (P.attnp[i] + P.g2[col] * vv);
        }
      }
    }
  }
}

template <int BM, int BN, int EPI>
__global__ __launch_bounds__(256) void gemm_v3(GemmP P) {
  extern __shared__ __align__(16) unsigned short smem[];
  gemm_body<BM, BN, EPI>(P, blockIdx.x, smem, smem + BM * 64);
}

// merged CA dispatch: blocks [0,split) = val GEMM (EPI1), rest = off/attw (EPI2)
template <int BM, int BN>
__global__ __launch_bounds__(256) void gemm_dual(GemmP Pv, GemmP Po, int split) {
  extern __shared__ __align__(16) unsigned short smem[];
  if ((int)blockIdx.x < split)
    gemm_body<BM, BN, 1>(Pv, blockIdx.x, smem, smem + BM * 64);
  else
    gemm_body<BM, BN, 2>(Po, blockIdx.x - split, smem, smem + BM * 64);
}

// ---------------- fused softmax + MS-deform bilinear sampling --------------
// (R4 configuration: raw logits in, per-16-lane-group softmax here.)
template <int NLEV>
__global__ __launch_bounds__(256) void ms_sample_fused(
    const unsigned short* __restrict__ value, const float* __restrict__ off,
    const float* __restrict__ logits, unsigned short* __restrict__ out) {
  const int nq = blockIdx.x;               // n*1024 + q
  const int wave = threadIdx.x >> 6, lane = threadIdx.x & 63;
  const int h = (wave << 2) + (lane >> 4);
  const int c = (lane & 15) << 2;          // channel base (0..60)
  const int q = nq & 1023, n = nq >> 10;
  const float* offp = off + ((size_t)nq * 16 + h) * (NLEV * 8);
  const float* lgp  = logits + ((size_t)nq * 16 + h) * (NLEV * 4);

  float lg[NLEV * 4];
  #pragma unroll
  for (int i = 0; i < NLEV; ++i) {
    float4 v = ((const float4*)lgp)[i];
    lg[4*i] = v.x; lg[4*i+1] = v.y; lg[4*i+2] = v.z; lg[4*i+3] = v.w;
  }
  float mx = lg[0];
  #pragma unroll
  for (int i = 1; i < NLEV * 4; ++i) mx = fmaxf(mx, lg[i]);
  float ssum = 0.f;
  #pragma unroll
  for (int i = 0; i < NLEV * 4; ++i) { lg[i] = __expf(lg[i] - mx); ssum += lg[i]; }
  const float inv = 1.f / ssum;

  const float fqx = (float)(q & 31), fqy = (float)(q >> 5);
  float a0 = 0.f, a1 = 0.f, a2 = 0.f, a3 = 0.f;

  #pragma unroll
  for (int l = 0; l < NLEV; ++l) {
    const unsigned short* vl =
        value + ((size_t)(n * NLEV + l) << 20) + h * 64 + c;
    #pragma unroll
    for (int p = 0; p < 4; ++p) {
      float2 o2 = ((const float2*)offp)[l * 4 + p];
      float aw = lg[l * 4 + p] * inv;
      float xx = fqx + o2.x, yy = fqy + o2.y;
      float xf = floorf(xx), yf = floorf(yy);
      float fx = xx - xf, fy = yy - yf;
      int ix = (int)xf, iy = (int)yf;
      int ix1 = ix + 1, iy1 = iy + 1;
      float vx0 = ((unsigned)ix  < 32u) ? 1.f : 0.f;
      float vx1 = ((unsigned)ix1 < 32u) ? 1.f : 0.f;
      float vy0 = ((unsigned)iy  < 32u) ? 1.f : 0.f;
      float vy1 = ((unsigned)iy1 < 32u) ? 1.f : 0.f;
      int cx0 = min(max(ix, 0), 31), cx1 = min(max(ix1, 0), 31);
      int cy0 = min(max(iy, 0), 31), cy1 = min(max(iy1, 0), 31);
      float w00 = (1.f - fx) * (1.f - fy) * vx0 * vy0 * aw;
      float w01 = fx * (1.f - fy) * vx1 * vy0 * aw;
      float w10 = (1.f - fx) * fy * vx0 * vy1 * aw;
      float w11 = fx * fy * vx1 * vy1 * aw;
      ushort4 u00 = *(const ushort4*)(vl + ((size_t)(cy0 * 32 + cx0) << 10));
      ushort4 u01 = *(const ushort4*)(vl + ((size_t)(cy0 * 32 + cx1) << 10));
      ushort4 u10 = *(const ushort4*)(vl + ((size_t)(cy1 * 32 + cx0) << 10));
      ushort4 u11 = *(const ushort4*)(vl + ((size_t)(cy1 * 32 + cx1) << 10));
      a0 += w00 * bf2f(u00.x) + w01 * bf2f(u01.x) + w10 * bf2f(u10.x) + w11 * bf2f(u11.x);
      a1 += w00 * bf2f(u00.y) + w01 * bf2f(u01.y) + w10 * bf2f(u10.y) + w11 * bf2f(u11.y);
      a2 += w00 * bf2f(u00.z) + w01 * bf2f(u01.z) + w10 * bf2f(u10.z) + w11 * bf2f(u11.z);
      a3 += w00 * bf2f(u00.w) + w01 * bf2f(u01.w) + w10 * bf2f(u10.w) + w11 * bf2f(u11.w);
    }
  }
  ushort4 r;
  r.x = f2bf(a0); r.y = f2bf(a1); r.z = f2bf(a2); r.w = f2bf(a3);
  *(ushort4*)(out + ((size_t)nq * 16 + h) * 64 + c) = r;
}

// ---------------------------------------------------------------------------
extern "C" void kernel_launch(void* const* d_in, const int* in_sizes, int n_in,
                              void* d_out, int out_size, void* d_ws,
                              size_t ws_size, hipStream_t stream) {
  (void)in_sizes; (void)n_in; (void)out_size; (void)ws_size;
  const float* src[4] = {(const float*)d_in[0], (const float*)d_in[1],
                         (const float*)d_in[2], (const float*)d_in[3]};
  const float* qn_g = (const float*)d_in[4];
  const float* qn_b = (const float*)d_in[5];
  const float* fn_g = (const float*)d_in[6];
  const float* fn_b = (const float*)d_in[7];
  const float* n1_g = (const float*)d_in[8];
  const float* n1_b = (const float*)d_in[9];
  const float* gamma1 = (const float*)d_in[10];
  const float* gamma2 = (const float*)d_in[11];
  const float* ca_vw = (const float*)d_in[12];
  const float* ca_vb = (const float*)d_in[13];
  const float* ca_ow = (const float*)d_in[14];
  const float* ca_ob = (const float*)d_in[15];
  const float* ca_aw = (const float*)d_in[16];
  const float* ca_ab = (const float*)d_in[17];
  const float* ca_pw = (const float*)d_in[18];
  const float* ca_pb = (const float*)d_in[19];
  const float* sa_vw = (const float*)d_in[20];
  const float* sa_vb = (const float*)d_in[21];
  const float* sa_ow = (const float*)d_in[22];
  const float* sa_ob = (const float*)d_in[23];
  const float* sa_aw = (const float*)d_in[24];
  const float* sa_ab = (const float*)d_in[25];
  const float* sa_pw = (const float*)d_in[26];
  const float* sa_pb = (const float*)d_in[27];

  // ---- workspace layout ----
  char* wsp = (char*)d_ws;
  size_t off = 0;
  auto alloc = [&](size_t bytes) {
    char* r = wsp + off;
    off = (off + bytes + 255) & ~(size_t)255;
    return r;
  };
  const size_t MB = 1024 * 1024;
  unsigned short* w_ca_vw = (unsigned short*)alloc(1024 * 1024 * 2);
  unsigned short* w_ca_ow = (unsigned short*)alloc(512 * 1024 * 2);
  unsigned short* w_ca_aw = (unsigned short*)alloc(256 * 1024 * 2);
  unsigned short* w_ca_pw = (unsigned short*)alloc(1024 * 1024 * 2);
  unsigned short* w_sa_vw = (unsigned short*)alloc(1024 * 1024 * 2);
  unsigned short* w_sa_ow = (unsigned short*)alloc(128 * 1024 * 2);
  unsigned short* w_sa_aw = (unsigned short*)alloc(64 * 1024 * 2);
  unsigned short* w_sa_pw = (unsigned short*)alloc(1024 * 1024 * 2);
  (void)w_ca_aw; (void)w_sa_ow; (void)w_sa_aw;
  char* R1 = alloc(32 * MB);  // f_ln bf16 | attn f32 + attn1 bf16 + samp_sa bf16
  char* R2 = alloc(32 * MB);  // val_ca bf16 | val_sa bf16
  char* R3 = alloc(8 * MB);   // q_ln bf16 | samp_ca bf16
  char* R4 = alloc(8 * MB);   // off_ca f32 | off_sa f32 + attw_sa f32
  char* R5 = alloc(4 * MB);   // attw_ca f32 (raw logits; softmax in sampler)

  unsigned short* f_ln    = (unsigned short*)R1;
  float*          attn    = (float*)R1;
  unsigned short* attn1   = (unsigned short*)(R1 + 16 * MB);
  unsigned short* samp_sa = (unsigned short*)(R1 + 24 * MB);
  unsigned short* val_ca  = (unsigned short*)R2;
  unsigned short* val_sa  = (unsigned short*)R2;
  unsigned short* q_ln    = (unsigned short*)R3;
  unsigned short* samp_ca = (unsigned short*)R3;
  float*          off_ca  = (float*)R4;
  float*          off_sa  = (float*)R4;
  float*          attw_sa = (float*)(R4 + 4 * MB);
  float*          attw_ca = (float*)R5;

  // ---- 1. merged weight conversion + LayerNorms ----
  CvtArgs ca;
  ca.src[0] = ca_vw; ca.src[1] = ca_ow; ca.src[2] = ca_aw; ca.src[3] = ca_pw;
  ca.src[4] = sa_vw; ca.src[5] = sa_ow; ca.src[6] = sa_aw; ca.src[7] = sa_pw;
  ca.dst = w_ca_vw;
  const int sizes4[8] = {262144, 131072, 65536, 262144, 262144, 32768, 16384, 262144};
  ca.off4[0] = 0;
  for (int i = 0; i < 8; ++i) ca.off4[i + 1] = ca.off4[i] + sizes4[i];
  LnArgs la;
  la.s[0] = src[0]; la.s[1] = src[1]; la.s[2] = src[2]; la.s[3] = src[3];
  la.fg = fn_g; la.fb = fn_b; la.qg = qn_g; la.qb = qn_b;
  la.f_out = f_ln; la.q_out = q_ln;
  prep_kernel<<<10176, 256, 0, stream>>>(ca, la);

  auto mkP = [](const unsigned short* A, const unsigned short* W, void* C,
                const float* b0, int M, int N, int K, int tilesM) {
    GemmP p{}; p.A = A; p.W = W; p.C = C; p.b0 = b0;
    p.M = M; p.N = N; p.K = K; p.tilesM = tilesM;
    return p;
  };

  // ---- 2. CA: merged value + off/attw GEMM (one dispatch) ----
  {
    GemmP pv = mkP(f_ln, w_ca_vw, val_ca, ca_vb, 16384, 1024, 1024, 128);
    GemmP po = mkP(q_ln, w_ca_ow, off_ca, ca_ob, 4096, 768, 1024, 32);
    po.C1 = attw_ca; po.b1 = ca_ab;
    gemm_dual<128, 128><<<1024 + 192, 256, 32768, stream>>>(pv, po, 1024);
  }

  // ---- 3. CA sampling + projection ----
  ms_sample_fused<4><<<4096, 256, 0, stream>>>(val_ca, off_ca, attw_ca, samp_ca);
  gemm_v3<64, 128, 0><<<64 * 8, 256, (64 + 128) * 64 * 2, stream>>>(
      mkP(samp_ca, w_ca_pw, attn, ca_pb, 4096, 1024, 1024, 64));

  // ---- 4. SA branch ----
  ln_wave_kernel<<<1024, 256, 0, stream>>>(attn, n1_g, n1_b, attn1);
  {
    GemmP p = mkP(attn1, w_sa_vw, val_sa, sa_vb, 4096, 1216, 1024, 64);
    p.C1 = off_sa; p.b1 = sa_ob; p.C2 = attw_sa; p.b2 = sa_ab;
    gemm_v3<64, 128, 3><<<64 * 10, 256, (64 + 128) * 64 * 2, stream>>>(p);
  }
  ms_sample_fused<1><<<4096, 256, 0, stream>>>(val_sa, off_sa, attw_sa, samp_sa);
  {
    GemmP p = mkP(samp_sa, w_sa_pw, d_out, sa_pb, 4096, 1024, 1024, 64);
    p.src3 = src[3]; p.g1 = gamma1; p.g2 = gamma2; p.attnp = attn;
    gemm_v3<64, 128, 4><<<64 * 8, 256, (64 + 128) * 64 * 2, stream>>>(p);
  }
}

// Round 9
// 368.684 us; speedup vs baseline: 1.0720x; 1.0061x over previous
//
#include <hip/hip_runtime.h>

// ---------------------------------------------------------------------------
// MSCrossAttnBlock on MI355X (gfx950).
// B=4, E=32, LQ=1024, D=1024, NH=16, DH=64, NP=4. All levels are 32x32.
// R8: GEMMs untouched (R4 config, measured 66us dual). Sampler v2: 8 heads/
//     wave, ushort8 gathers (half instrs+waves), XCD-locality swizzle.
//     attn kept bf16 end-to-end; prep emits q-LN from the src3 read.
//     8 dispatches.
// ---------------------------------------------------------------------------

#define DEV __device__ __forceinline__

typedef float f32x4 __attribute__((ext_vector_type(4)));
typedef __bf16 bf16x8 __attribute__((ext_vector_type(8)));
typedef unsigned short u16x8 __attribute__((ext_vector_type(8)));

DEV unsigned short f2bf(float f) {
  union { float f; unsigned u; } a; a.f = f;
  unsigned r = a.u + 0x7fffu + ((a.u >> 16) & 1u);
  return (unsigned short)(r >> 16);
}
DEV float bf2f(unsigned short h) {
  union { unsigned u; float f; } a; a.u = ((unsigned)h) << 16;
  return a.f;
}

// ---------------- merged prep: weight cvt + all LayerNorms -----------------
struct CvtArgs {
  const float* src[8];
  unsigned short* dst;
  int off4[9];  // prefix sums, float4 units
};
struct LnArgs {
  const float* s[4];
  const float* fg; const float* fb; const float* qg; const float* qb;
  unsigned short* f_out; unsigned short* q_out;
};

DEV void ln_stats(const float* __restrict__ xr, float4 (&v)[4], float& mean,
                  float& rstd) {
  const int lane = threadIdx.x & 63;
  float s = 0.f, s2 = 0.f;
  #pragma unroll
  for (int j = 0; j < 4; ++j) {
    v[j] = ((const float4*)xr)[lane + 64 * j];
    s  += v[j].x + v[j].y + v[j].z + v[j].w;
    s2 += v[j].x*v[j].x + v[j].y*v[j].y + v[j].z*v[j].z + v[j].w*v[j].w;
  }
  #pragma unroll
  for (int o = 32; o; o >>= 1) { s += __shfl_xor(s, o); s2 += __shfl_xor(s2, o); }
  mean = s * (1.f / 1024.f);
  rstd = rsqrtf(s2 * (1.f / 1024.f) - mean * mean + 1e-6f);
}

DEV void ln_apply(const float4 (&v)[4], float mean, float rstd,
                  const float* __restrict__ g, const float* __restrict__ b,
                  unsigned short* __restrict__ op_row) {
  const int lane = threadIdx.x & 63;
  #pragma unroll
  for (int j = 0; j < 4; ++j) {
    float4 gg = ((const float4*)g)[lane + 64 * j];
    float4 bb = ((const float4*)b)[lane + 64 * j];
    ushort4 r;
    r.x = f2bf((v[j].x - mean) * rstd * gg.x + bb.x);
    r.y = f2bf((v[j].y - mean) * rstd * gg.y + bb.y);
    r.z = f2bf((v[j].z - mean) * rstd * gg.z + bb.z);
    r.w = f2bf((v[j].w - mean) * rstd * gg.w + bb.w);
    ((ushort4*)op_row)[lane + 64 * j] = r;
  }
}

// blocks [0,5056): cvt; [5056,9152): feat-LN rows (src3 rows also emit q-LN).
__global__ __launch_bounds__(256) void prep_kernel(CvtArgs a, LnArgs L) {
  if (blockIdx.x < 5056) {
    int i = blockIdx.x * 256 + threadIdx.x;  // float4 index, exact grid
    int seg = 0;
    #pragma unroll
    for (int s = 1; s < 8; ++s) seg += (i >= a.off4[s]) ? 1 : 0;
    const float4 v = ((const float4*)a.src[seg])[i - a.off4[seg]];
    unsigned short* o = a.dst + (size_t)i * 4;
    o[0] = f2bf(v.x); o[1] = f2bf(v.y); o[2] = f2bf(v.z); o[3] = f2bf(v.w);
  } else {
    int row = (blockIdx.x - 5056) * 4 + (threadIdx.x >> 6);  // 0..16383
    int l = row >> 12, inner = row & 4095;
    int orow = (inner >> 10) * 4096 + l * 1024 + (inner & 1023);
    float4 v[4]; float mean, rstd;
    ln_stats(L.s[l] + (size_t)inner * 1024, v, mean, rstd);
    ln_apply(v, mean, rstd, L.fg, L.fb, L.f_out + (size_t)orow * 1024);
    if (l == 3)  // src3: emit q-LN from the same read/stats
      ln_apply(v, mean, rstd, L.qg, L.qb, L.q_out + (size_t)inner * 1024);
  }
}

// LN over bf16 input (attn -> attn1), wave per row.
__global__ __launch_bounds__(256) void ln_wave_bf16(
    const unsigned short* __restrict__ x, const float* __restrict__ g,
    const float* __restrict__ b, unsigned short* __restrict__ out) {
  int row = blockIdx.x * 4 + (threadIdx.x >> 6);
  const int lane = threadIdx.x & 63;
  const unsigned short* xr = x + (size_t)row * 1024;
  float e[16];
  float s = 0.f, s2 = 0.f;
  #pragma unroll
  for (int j = 0; j < 2; ++j) {
    u16x8 u = ((const u16x8*)xr)[lane + 64 * j];
    #pragma unroll
    for (int k = 0; k < 8; ++k) {
      float f = bf2f(u[k]);
      e[j * 8 + k] = f; s += f; s2 += f * f;
    }
  }
  #pragma unroll
  for (int o = 32; o; o >>= 1) { s += __shfl_xor(s, o); s2 += __shfl_xor(s2, o); }
  const float mean = s * (1.f / 1024.f);
  const float rstd = rsqrtf(s2 * (1.f / 1024.f) - mean * mean + 1e-6f);
  #pragma unroll
  for (int j = 0; j < 2; ++j) {
    u16x8 r;
    #pragma unroll
    for (int k = 0; k < 8; ++k) {
      int idx = (lane + 64 * j) * 8 + k;
      r[k] = f2bf((e[j * 8 + k] - mean) * rstd * g[idx] + b[idx]);
    }
    ((u16x8*)(out + (size_t)row * 1024))[lane + 64 * j] = r;
  }
}

// ---------------- bf16 MFMA GEMM, 16x16x32 inner, swizzled LDS -------------
// (R4 configuration — measured-good; DO NOT add shfl/expf to epilogues,
//  R5-R7 showed that regresses the whole dispatch 66->85us.)
// EPI: 1=bf16, 2=CA split(off512 f32 | attw256 f32 raw logits),
//      3=SA split(val1024 bf16 | off128 f32 | attw64 f32 raw logits),
//      4=final combine (attnp bf16) -> d_out f32.
struct GemmP {
  const unsigned short* A; const unsigned short* W;
  void* C; void* C1; void* C2;
  const float* b0; const float* b1; const float* b2;
  const float* src3; const float* g1; const float* g2;
  const unsigned short* attnp;
  int M, N, K, tilesM;
};

template <int BM, int BN, int EPI>
DEV void gemm_body(const GemmP& P, int id, unsigned short* sA,
                   unsigned short* sB) {
  constexpr int WMT = BM / 2, WNT = BN / 2;
  constexpr int MF = WMT / 16, NF = WNT / 16;
  constexpr int PA = BM / 64, PB = BN / 64;    // granule passes per sub-tile
  const int tid = threadIdx.x;
  const int wave = tid >> 6, lane = tid & 63;
  const int wm = (wave & 1) * WMT, wn = (wave >> 1) * WNT;
  const int m0 = (id % P.tilesM) * BM;
  const int n0 = (id / P.tilesM) * BN;
  const int lq = lane >> 4, lm = lane & 15;
  const int r16 = lane >> 2;                    // staging: row within granule
  const int cst = lane & 3;                     // staging: slot within row
  const int csrc = cst ^ ((r16 >> 1) & 3);      // global k-chunk for slot
  const int aslot = lq ^ ((lm >> 1) & 3);       // read slot for chunk lq

  f32x4 acc[MF][NF] = {};
  bf16x8 ald[2][PA], bld[2][PB];

  #pragma unroll 1
  for (int k0 = 0; k0 < P.K; k0 += 64) {
    #pragma unroll
    for (int s = 0; s < 2; ++s) {
      #pragma unroll
      for (int p = 0; p < PA; ++p) {
        int grow = m0 + (wave + 4 * p) * 16 + r16;
        ald[s][p] = *(const bf16x8*)(P.A + (size_t)grow * P.K + k0 + s * 32 + csrc * 8);
      }
      #pragma unroll
      for (int p = 0; p < PB; ++p) {
        int grow = min(n0 + (wave + 4 * p) * 16 + r16, P.N - 1);
        bld[s][p] = *(const bf16x8*)(P.W + (size_t)grow * P.K + k0 + s * 32 + csrc * 8);
      }
    }
    __syncthreads();  // prev iteration's LDS reads complete
    #pragma unroll
    for (int s = 0; s < 2; ++s) {
      #pragma unroll
      for (int p = 0; p < PA; ++p)
        *(bf16x8*)(sA + s * BM * 32 + (wave + 4 * p) * 512 + (r16 * 4 + cst) * 8) = ald[s][p];
      #pragma unroll
      for (int p = 0; p < PB; ++p)
        *(bf16x8*)(sB + s * BN * 32 + (wave + 4 * p) * 512 + (r16 * 4 + cst) * 8) = bld[s][p];
    }
    __syncthreads();
    #pragma unroll
    for (int s = 0; s < 2; ++s) {
      bf16x8 af[MF], bfr[NF];
      #pragma unroll
      for (int mi = 0; mi < MF; ++mi)
        af[mi] = *(const bf16x8*)(sA + s * BM * 32 + ((wm >> 4) + mi) * 512 + lm * 32 + aslot * 8);
      #pragma unroll
      for (int ni = 0; ni < NF; ++ni)
        bfr[ni] = *(const bf16x8*)(sB + s * BN * 32 + ((wn >> 4) + ni) * 512 + lm * 32 + aslot * 8);
      #pragma unroll
      for (int mi = 0; mi < MF; ++mi)
        #pragma unroll
        for (int ni = 0; ni < NF; ++ni)
          acc[mi][ni] = __builtin_amdgcn_mfma_f32_16x16x32_bf16(
              af[mi], bfr[ni], acc[mi][ni], 0, 0, 0);
    }
  }

  #pragma unroll
  for (int mi = 0; mi < MF; ++mi) {
    #pragma unroll
    for (int ni = 0; ni < NF; ++ni) {
      const int col = n0 + wn + ni * 16 + lm;
      #pragma unroll
      for (int r2 = 0; r2 < 4; ++r2) {
        const int row = m0 + wm + mi * 16 + lq * 4 + r2;
        float v = acc[mi][ni][r2];
        if constexpr (EPI == 1) {
          ((unsigned short*)P.C)[(size_t)row * 1024 + col] = f2bf(v + P.b0[col]);
        } else if constexpr (EPI == 2) {
          if (col < 512)
            ((float*)P.C)[(size_t)row * 512 + col] = v + P.b0[col];
          else
            ((float*)P.C1)[(size_t)row * 256 + col - 512] = v + P.b1[col - 512];
        } else if constexpr (EPI == 3) {
          if (col < 1024)
            ((unsigned short*)P.C)[(size_t)row * 1024 + col] = f2bf(v + P.b0[col]);
          else if (col < 1152)
            ((float*)P.C1)[(size_t)row * 128 + col - 1024] = v + P.b1[col - 1024];
          else if (col < 1216)
            ((float*)P.C2)[(size_t)row * 64 + col - 1152] = v + P.b2[col - 1152];
        } else {  // EPI == 4: out = src3 + g1*(attn_bf16 + g2*(v+b))
          size_t i = (size_t)row * 1024 + col;
          float vv = v + P.b0[col];
          float at = bf2f(P.attnp[i]);
          ((float*)P.C)[i] = P.src3[i] + P.g1[col] * (at + P.g2[col] * vv);
        }
      }
    }
  }
}

template <int BM, int BN, int EPI>
__global__ __launch_bounds__(256) void gemm_v3(GemmP P) {
  extern __shared__ __align__(16) unsigned short smem[];
  gemm_body<BM, BN, EPI>(P, blockIdx.x, smem, smem + BM * 64);
}

// merged CA dispatch: blocks [0,split) = val GEMM (EPI1), rest = off/attw (EPI2)
template <int BM, int BN>
__global__ __launch_bounds__(256) void gemm_dual(GemmP Pv, GemmP Po, int split) {
  extern __shared__ __align__(16) unsigned short smem[];
  if ((int)blockIdx.x < split)
    gemm_body<BM, BN, 1>(Pv, blockIdx.x, smem, smem + BM * 64);
  else
    gemm_body<BM, BN, 2>(Po, blockIdx.x - split, smem, smem + BM * 64);
}

// ---------------- fused softmax + MS-deform sampling, v2 -------------------
// 2048 blocks, 2 nq each; wave handles 8 heads; lane = (h&7)<<3 | c/8;
// ushort8 (16B) gathers. XCD-locality swizzle: xcd=b&7 -> n=(b&7)>>1, so each
// XCD's gather working set is value[n] (8 MB CA / 2 MB SA) instead of all 32.
template <int NLEV>
__global__ __launch_bounds__(256) void ms_sample_v2(
    const unsigned short* __restrict__ value, const float* __restrict__ off,
    const float* __restrict__ logits, unsigned short* __restrict__ out) {
  const int b = blockIdx.x;
  const int wave = threadIdx.x >> 6, lane = threadIdx.x & 63;
  const int n = (b & 7) >> 1;
  const int q = ((b & 1) << 9) + ((b >> 3) << 1) + (wave >> 1);
  const int nq = (n << 10) + q;
  const int h = ((wave & 1) << 3) + (lane >> 3);
  const int c = (lane & 7) << 3;           // channel base (0..56)
  const float* offp = off + ((size_t)nq * 16 + h) * (NLEV * 8);
  const float* lgp  = logits + ((size_t)nq * 16 + h) * (NLEV * 4);

  float lg[NLEV * 4];
  #pragma unroll
  for (int i = 0; i < NLEV; ++i) {
    float4 v = ((const float4*)lgp)[i];
    lg[4*i] = v.x; lg[4*i+1] = v.y; lg[4*i+2] = v.z; lg[4*i+3] = v.w;
  }
  float mx = lg[0];
  #pragma unroll
  for (int i = 1; i < NLEV * 4; ++i) mx = fmaxf(mx, lg[i]);
  float ssum = 0.f;
  #pragma unroll
  for (int i = 0; i < NLEV * 4; ++i) { lg[i] = __expf(lg[i] - mx); ssum += lg[i]; }
  const float inv = 1.f / ssum;

  const float fqx = (float)(q & 31), fqy = (float)(q >> 5);
  float a[8] = {};

  #pragma unroll
  for (int l = 0; l < NLEV; ++l) {
    const unsigned short* vl =
        value + ((size_t)(n * NLEV + l) << 20) + h * 64 + c;
    #pragma unroll
    for (int p = 0; p < 4; ++p) {
      float2 o2 = ((const float2*)offp)[l * 4 + p];
      float aw = lg[l * 4 + p] * inv;
      float xx = fqx + o2.x, yy = fqy + o2.y;
      float xf = floorf(xx), yf = floorf(yy);
      float fx = xx - xf, fy = yy - yf;
      int ix = (int)xf, iy = (int)yf;
      int ix1 = ix + 1, iy1 = iy + 1;
      float vx0 = ((unsigned)ix  < 32u) ? 1.f : 0.f;
      float vx1 = ((unsigned)ix1 < 32u) ? 1.f : 0.f;
      float vy0 = ((unsigned)iy  < 32u) ? 1.f : 0.f;
      float vy1 = ((unsigned)iy1 < 32u) ? 1.f : 0.f;
      int cx0 = min(max(ix, 0), 31), cx1 = min(max(ix1, 0), 31);
      int cy0 = min(max(iy, 0), 31), cy1 = min(max(iy1, 0), 31);
      float w00 = (1.f - fx) * (1.f - fy) * vx0 * vy0 * aw;
      float w01 = fx * (1.f - fy) * vx1 * vy0 * aw;
      float w10 = (1.f - fx) * fy * vx0 * vy1 * aw;
      float w11 = fx * fy * vx1 * vy1 * aw;
      u16x8 u00 = *(const u16x8*)(vl + ((size_t)(cy0 * 32 + cx0) << 10));
      u16x8 u01 = *(const u16x8*)(vl + ((size_t)(cy0 * 32 + cx1) << 10));
      u16x8 u10 = *(const u16x8*)(vl + ((size_t)(cy1 * 32 + cx0) << 10));
      u16x8 u11 = *(const u16x8*)(vl + ((size_t)(cy1 * 32 + cx1) << 10));
      #pragma unroll
      for (int k = 0; k < 8; ++k)
        a[k] += w00 * bf2f(u00[k]) + w01 * bf2f(u01[k]) +
                w10 * bf2f(u10[k]) + w11 * bf2f(u11[k]);
    }
  }
  u16x8 r;
  #pragma unroll
  for (int k = 0; k < 8; ++k) r[k] = f2bf(a[k]);
  *(u16x8*)(out + ((size_t)nq * 16 + h) * 64 + c) = r;
}

// ---------------------------------------------------------------------------
extern "C" void kernel_launch(void* const* d_in, const int* in_sizes, int n_in,
                              void* d_out, int out_size, void* d_ws,
                              size_t ws_size, hipStream_t stream) {
  (void)in_sizes; (void)n_in; (void)out_size; (void)ws_size;
  const float* src[4] = {(const float*)d_in[0], (const float*)d_in[1],
                         (const float*)d_in[2], (const float*)d_in[3]};
  const float* qn_g = (const float*)d_in[4];
  const float* qn_b = (const float*)d_in[5];
  const float* fn_g = (const float*)d_in[6];
  const float* fn_b = (const float*)d_in[7];
  const float* n1_g = (const float*)d_in[8];
  const float* n1_b = (const float*)d_in[9];
  const float* gamma1 = (const float*)d_in[10];
  const float* gamma2 = (const float*)d_in[11];
  const float* ca_vw = (const float*)d_in[12];
  const float* ca_vb = (const float*)d_in[13];
  const float* ca_ow = (const float*)d_in[14];
  const float* ca_ob = (const float*)d_in[15];
  const float* ca_aw = (const float*)d_in[16];
  const float* ca_ab = (const float*)d_in[17];
  const float* ca_pw = (const float*)d_in[18];
  const float* ca_pb = (const float*)d_in[19];
  const float* sa_vw = (const float*)d_in[20];
  const float* sa_vb = (const float*)d_in[21];
  const float* sa_ow = (const float*)d_in[22];
  const float* sa_ob = (const float*)d_in[23];
  const float* sa_aw = (const float*)d_in[24];
  const float* sa_ab = (const float*)d_in[25];
  const float* sa_pw = (const float*)d_in[26];
  const float* sa_pb = (const float*)d_in[27];

  // ---- workspace layout ----
  char* wsp = (char*)d_ws;
  size_t off = 0;
  auto alloc = [&](size_t bytes) {
    char* r = wsp + off;
    off = (off + bytes + 255) & ~(size_t)255;
    return r;
  };
  const size_t MB = 1024 * 1024;
  unsigned short* w_ca_vw = (unsigned short*)alloc(1024 * 1024 * 2);
  unsigned short* w_ca_ow = (unsigned short*)alloc(512 * 1024 * 2);
  unsigned short* w_ca_aw = (unsigned short*)alloc(256 * 1024 * 2);
  unsigned short* w_ca_pw = (unsigned short*)alloc(1024 * 1024 * 2);
  unsigned short* w_sa_vw = (unsigned short*)alloc(1024 * 1024 * 2);
  unsigned short* w_sa_ow = (unsigned short*)alloc(128 * 1024 * 2);
  unsigned short* w_sa_aw = (unsigned short*)alloc(64 * 1024 * 2);
  unsigned short* w_sa_pw = (unsigned short*)alloc(1024 * 1024 * 2);
  (void)w_ca_aw; (void)w_sa_ow; (void)w_sa_aw;
  char* R1 = alloc(32 * MB);  // f_ln bf16 | attn bf16 + attn1 bf16 + samp_sa bf16
  char* R2 = alloc(32 * MB);  // val_ca bf16 | val_sa bf16
  char* R3 = alloc(8 * MB);   // q_ln bf16 | samp_ca bf16
  char* R4 = alloc(8 * MB);   // off_ca f32 | off_sa f32 + attw_sa f32
  char* R5 = alloc(4 * MB);   // attw_ca f32 (raw logits; softmax in sampler)

  unsigned short* f_ln    = (unsigned short*)R1;
  unsigned short* attn    = (unsigned short*)R1;            // bf16, 8 MB
  unsigned short* attn1   = (unsigned short*)(R1 + 8 * MB);
  unsigned short* samp_sa = (unsigned short*)(R1 + 16 * MB);
  unsigned short* val_ca  = (unsigned short*)R2;
  unsigned short* val_sa  = (unsigned short*)R2;
  unsigned short* q_ln    = (unsigned short*)R3;
  unsigned short* samp_ca = (unsigned short*)R3;
  float*          off_ca  = (float*)R4;
  float*          off_sa  = (float*)R4;
  float*          attw_sa = (float*)(R4 + 4 * MB);
  float*          attw_ca = (float*)R5;

  // ---- 1. merged weight conversion + LayerNorms ----
  CvtArgs ca;
  ca.src[0] = ca_vw; ca.src[1] = ca_ow; ca.src[2] = ca_aw; ca.src[3] = ca_pw;
  ca.src[4] = sa_vw; ca.src[5] = sa_ow; ca.src[6] = sa_aw; ca.src[7] = sa_pw;
  ca.dst = w_ca_vw;
  const int sizes4[8] = {262144, 131072, 65536, 262144, 262144, 32768, 16384, 262144};
  ca.off4[0] = 0;
  for (int i = 0; i < 8; ++i) ca.off4[i + 1] = ca.off4[i] + sizes4[i];
  LnArgs la;
  la.s[0] = src[0]; la.s[1] = src[1]; la.s[2] = src[2]; la.s[3] = src[3];
  la.fg = fn_g; la.fb = fn_b; la.qg = qn_g; la.qb = qn_b;
  la.f_out = f_ln; la.q_out = q_ln;
  prep_kernel<<<5056 + 4096, 256, 0, stream>>>(ca, la);

  auto mkP = [](const unsigned short* A, const unsigned short* W, void* C,
                const float* b0, int M, int N, int K, int tilesM) {
    GemmP p{}; p.A = A; p.W = W; p.C = C; p.b0 = b0;
    p.M = M; p.N = N; p.K = K; p.tilesM = tilesM;
    return p;
  };

  // ---- 2. CA: merged value + off/attw GEMM (one dispatch) ----
  {
    GemmP pv = mkP(f_ln, w_ca_vw, val_ca, ca_vb, 16384, 1024, 1024, 128);
    GemmP po = mkP(q_ln, w_ca_ow, off_ca, ca_ob, 4096, 768, 1024, 32);
    po.C1 = attw_ca; po.b1 = ca_ab;
    gemm_dual<128, 128><<<1024 + 192, 256, 32768, stream>>>(pv, po, 1024);
  }

  // ---- 3. CA sampling + projection (attn stored bf16) ----
  ms_sample_v2<4><<<2048, 256, 0, stream>>>(val_ca, off_ca, attw_ca, samp_ca);
  gemm_v3<64, 128, 1><<<64 * 8, 256, (64 + 128) * 64 * 2, stream>>>(
      mkP(samp_ca, w_ca_pw, attn, ca_pb, 4096, 1024, 1024, 64));

  // ---- 4. SA branch ----
  ln_wave_bf16<<<1024, 256, 0, stream>>>(attn, n1_g, n1_b, attn1);
  {
    GemmP p = mkP(attn1, w_sa_vw, val_sa, sa_vb, 4096, 1216, 1024, 64);
    p.C1 = off_sa; p.b1 = sa_ob; p.C2 = attw_sa; p.b2 = sa_ab;
    gemm_v3<64, 128, 3><<<64 * 10, 256, (64 + 128) * 64 * 2, stream>>>(p);
  }
  ms_sample_v2<1><<<2048, 256, 0, stream>>>(val_sa, off_sa, attw_sa, samp_sa);
  {
    GemmP p = mkP(samp_sa, w_sa_pw, d_out, sa_pb, 4096, 1024, 1024, 64);
    p.src3 = src[3]; p.g1 = gamma1; p.g2 = gamma2; p.attnp = attn;
    gemm_v3<64, 128, 4><<<64 * 8, 256, (64 + 128) * 64 * 2, stream>>>(p);
  }
}